// Round 12
// baseline (141.193 us; speedup 1.0000x reference)
//
#include <hip/hip_runtime.h>
#include <hip/hip_fp16.h>
#include <math.h>

#define HW     65536
#define WIDTH  256
#define HEIGHT 256

typedef __attribute__((ext_vector_type(8))) short bf16x8;
typedef __attribute__((ext_vector_type(4))) float f32x4;

__device__ __forceinline__ float relu_f(float x){ return x > 0.f ? x : 0.f; }
__device__ __forceinline__ unsigned int f2bf(float x){
    union { float f; unsigned int u; } v; v.f = x;
    unsigned int r = v.u + 0x7fffu + ((v.u >> 16) & 1u);   // RNE
    return r >> 16;
}
__device__ __forceinline__ float bfbits2f(unsigned int lo16){
    union { unsigned int u; float f; } v; v.u = lo16 << 16; return v.f;
}
__device__ __forceinline__ float h2f(unsigned int bits16){
    __half h = *(__half*)&bits16; return __half2float(h);
}

// ---------------- K0: prep — fold BN, pack MFMA A-fragments ----------------
__global__ void k_prep(const float* __restrict__ pw_w, const float* __restrict__ aff_w,
                       const float* __restrict__ g1, const float* __restrict__ b1,
                       const float* __restrict__ m1, const float* __restrict__ v1,
                       const float* __restrict__ g2, const float* __restrict__ b2,
                       const float* __restrict__ m2, const float* __restrict__ v2,
                       float* __restrict__ scsh, unsigned short* __restrict__ pwA,
                       unsigned short* __restrict__ affA){
    int t = threadIdx.x;
    for (int i = t; i < 4096; i += 256){
        int e = i & 7, l = (i >> 3) & 63, ks = (i >> 9) & 1, ct = i >> 10;
        int co = ct * 16 + (l & 15);
        int ci = ks * 32 + (l >> 4) * 8 + e;
        pwA[i] = (unsigned short)f2bf(pw_w[co * 64 + ci]);
    }
    for (int i = t; i < 1024; i += 256){
        int e = i & 7, l = (i >> 3) & 63, ks = i >> 9;
        int p = l & 15, k = ks * 32 + (l >> 4) * 8 + e;
        affA[i] = (unsigned short)f2bf(aff_w[p * 64 + k]);
    }
    if (t < 64){
        float s = g1[t] * rsqrtf(v1[t] + 1e-5f);
        scsh[t]       = s;
        scsh[64 + t]  = b1[t] - m1[t] * s;
        float s2 = g2[t] * rsqrtf(v2[t] + 1e-5f);
        scsh[128 + t] = s2;
        scsh[192 + t] = b2[t] - m2[t] * s2;
    }
}

// ---------------- K2: full-row dw3x3 (pipelined) -> MFMA pw -> MFMA affinity -> f16 logits ----------------
__global__ __launch_bounds__(256, 4) void k_conv_aff(
    const float* __restrict__ feat, const float* __restrict__ dw_w,
    const float* __restrict__ scsh, const unsigned short* __restrict__ pwA,
    const unsigned short* __restrict__ affA,
    unsigned short* __restrict__ logitsH, float* __restrict__ ei)
{
    __shared__ unsigned short x1u[256 * 68];
    __shared__ float eibuf[4][256];
    int t = threadIdx.x;
    int lane = t & 63;
    int wu = __builtin_amdgcn_readfirstlane(t >> 6);
    int orig = blockIdx.x;
    int flat = (orig & 7) * 256 + (orig >> 3);   // XCD-bijective (2048 = 8*256)
    int b = flat >> 8, h = flat & 255;

    const bf16x8* pwA8 = (const bf16x8*)pwA;
    bf16x8 apw0 = pwA8[(wu * 2 + 0) * 64 + lane];
    bf16x8 apw1 = pwA8[(wu * 2 + 1) * 64 + lane];
    const bf16x8* affA8 = (const bf16x8*)affA;
    bf16x8 aaf0 = affA8[lane];
    bf16x8 aaf1 = affA8[64 + lane];
    int lcol = lane & 15, pq = lane >> 4;
    int cb = wu * 16 + pq * 4;
    float4 sc2v = *(const float4*)(scsh + 128 + cb);
    float4 sh2v = *(const float4*)(scsh + 192 + cb);

    // ---- phase A: depthwise 3x3, 4 px/lane, software-pipelined ci-pair loop
    int px0 = lane * 4;
    const float* fb = feat + (size_t)b * 64 * HW;
    int hh0 = (h > 0) ? h - 1 : 0;
    int hh2 = (h < 255) ? h + 1 : 255;
    float rw0 = (h > 0) ? 1.f : 0.f;
    float rw2 = (h < 255) ? 1.f : 0.f;
    int   roff0 = hh0 * WIDTH, roff1 = h * WIDTH, roff2 = hh2 * WIDTH;
    float mx = 0.f, my = 0.f, mz = 0.f, mw = 0.f;
    int swz = ((lane >> 2) & 7) << 1;

    float4 cur0[3], cur1[3], nxt0[3], nxt1[3];
    {
        const float* p0 = fb + (size_t)(wu * 16) * HW + px0;
        const float* p1 = p0 + HW;
        cur0[0] = *(const float4*)(p0 + roff0);
        cur0[1] = *(const float4*)(p0 + roff1);
        cur0[2] = *(const float4*)(p0 + roff2);
        cur1[0] = *(const float4*)(p1 + roff0);
        cur1[1] = *(const float4*)(p1 + roff1);
        cur1[2] = *(const float4*)(p1 + roff2);
    }
    #pragma unroll
    for (int cp = 0; cp < 8; cp++){
        int ci0 = wu * 16 + cp * 2;
        int ci1 = ci0 + 1;
        if (cp < 7){
            const float* p0 = fb + (size_t)(ci0 + 2) * HW + px0;
            const float* p1 = p0 + HW;
            nxt0[0] = *(const float4*)(p0 + roff0);
            nxt0[1] = *(const float4*)(p0 + roff1);
            nxt0[2] = *(const float4*)(p0 + roff2);
            nxt1[0] = *(const float4*)(p1 + roff0);
            nxt1[1] = *(const float4*)(p1 + roff1);
            nxt1[2] = *(const float4*)(p1 + roff2);
        }
        float a00=0.f,a01=0.f,a02=0.f,a03=0.f, a10=0.f,a11=0.f,a12=0.f,a13=0.f;
        #pragma unroll
        for (int r = 0; r < 3; r++){
            float rwf = (r == 0) ? rw0 : ((r == 1) ? 1.f : rw2);
            float4 v0 = cur0[r];
            float4 v1 = cur1[r];
            float w00 = dw_w[ci0*9 + r*3 + 0] * rwf;
            float w01 = dw_w[ci0*9 + r*3 + 1] * rwf;
            float w02 = dw_w[ci0*9 + r*3 + 2] * rwf;
            float w10 = dw_w[ci1*9 + r*3 + 0] * rwf;
            float w11 = dw_w[ci1*9 + r*3 + 1] * rwf;
            float w12 = dw_w[ci1*9 + r*3 + 2] * rwf;
            float lf0 = __shfl_up(v0.w, 1);  if (lane == 0)  lf0 = 0.f;
            float rt0 = __shfl_down(v0.x, 1); if (lane == 63) rt0 = 0.f;
            float lf1 = __shfl_up(v1.w, 1);  if (lane == 0)  lf1 = 0.f;
            float rt1 = __shfl_down(v1.x, 1); if (lane == 63) rt1 = 0.f;
            a00 += lf0*w00 + v0.x*w01 + v0.y*w02;
            a01 += v0.x*w00 + v0.y*w01 + v0.z*w02;
            a02 += v0.y*w00 + v0.z*w01 + v0.w*w02;
            a03 += v0.z*w00 + v0.w*w01 + rt0*w02;
            a10 += lf1*w10 + v1.x*w11 + v1.y*w12;
            a11 += v1.x*w10 + v1.y*w11 + v1.z*w12;
            a12 += v1.y*w10 + v1.z*w11 + v1.w*w12;
            a13 += v1.z*w10 + v1.w*w11 + rt1*w12;
            if (r == 1){
                mx += v0.x + v1.x; my += v0.y + v1.y;
                mz += v0.z + v1.z; mw += v0.w + v1.w;
            }
        }
        float s0 = scsh[ci0], o0 = scsh[64 + ci0];
        float s1 = scsh[ci1], o1 = scsh[64 + ci1];
        int dwi = ((wu * 8 + cp) ^ swz) * 2;
        unsigned int pk0 = f2bf(relu_f(fmaf(a00,s0,o0))) | (f2bf(relu_f(fmaf(a10,s1,o1))) << 16);
        unsigned int pk1 = f2bf(relu_f(fmaf(a01,s0,o0))) | (f2bf(relu_f(fmaf(a11,s1,o1))) << 16);
        unsigned int pk2 = f2bf(relu_f(fmaf(a02,s0,o0))) | (f2bf(relu_f(fmaf(a12,s1,o1))) << 16);
        unsigned int pk3 = f2bf(relu_f(fmaf(a03,s0,o0))) | (f2bf(relu_f(fmaf(a13,s1,o1))) << 16);
        *(unsigned int*)&x1u[(px0 + 0) * 68 + dwi] = pk0;
        *(unsigned int*)&x1u[(px0 + 1) * 68 + dwi] = pk1;
        *(unsigned int*)&x1u[(px0 + 2) * 68 + dwi] = pk2;
        *(unsigned int*)&x1u[(px0 + 3) * 68 + dwi] = pk3;
        #pragma unroll
        for (int r = 0; r < 3; r++){ cur0[r] = nxt0[r]; cur1[r] = nxt1[r]; }
    }
    *(float4*)&eibuf[wu][px0] = make_float4(mx, my, mz, mw);
    __syncthreads();
    {
        float m = (eibuf[0][t] + eibuf[1][t]) + (eibuf[2][t] + eibuf[3][t]);
        ei[(size_t)b * HW + h * WIDTH + t] = m * (1.f / 64.f);
    }

    // ---- phase B
    int k0d = pq * 4;
    #pragma unroll
    for (int half = 0; half < 2; half++){
        f32x4 accB[8];
        #pragma unroll
        for (int q = 0; q < 8; q++){
            int jt = half * 8 + q;
            int swzj = (jt & 7) << 1;
            const unsigned short* rowp = &x1u[(jt * 16 + lcol) * 68];
            union { bf16x8 v; uint2 u[2]; } b0, b1;
            b0.u[0] = *(const uint2*)&rowp[((k0d)          ^ swzj) * 2];
            b0.u[1] = *(const uint2*)&rowp[((k0d + 2)      ^ swzj) * 2];
            b1.u[0] = *(const uint2*)&rowp[((16 + k0d)     ^ swzj) * 2];
            b1.u[1] = *(const uint2*)&rowp[((16 + k0d + 2) ^ swzj) * 2];
            f32x4 acc = {0.f, 0.f, 0.f, 0.f};
            acc = __builtin_amdgcn_mfma_f32_16x16x32_bf16(apw0, b0.v, acc, 0, 0, 0);
            acc = __builtin_amdgcn_mfma_f32_16x16x32_bf16(apw1, b1.v, acc, 0, 0, 0);
            accB[q] = acc;
        }
        __syncthreads();
        #pragma unroll
        for (int q = 0; q < 8; q++){
            int jt = half * 8 + q;
            int swzj = (jt & 7) << 1;
            f32x4 acc = accB[q];
            unsigned int y0 = f2bf(relu_f(fmaf(acc[0], sc2v.x, sh2v.x)))
                            | (f2bf(relu_f(fmaf(acc[1], sc2v.y, sh2v.y))) << 16);
            unsigned int y1 = f2bf(relu_f(fmaf(acc[2], sc2v.z, sh2v.z)))
                            | (f2bf(relu_f(fmaf(acc[3], sc2v.w, sh2v.w))) << 16);
            int D = (wu * 8 + pq * 2) ^ swzj;
            *(uint2*)&x1u[(jt * 16 + lcol) * 68 + D * 2] = make_uint2(y0, y1);
        }
    }
    __syncthreads();

    // ---- phase C: affinity GEMM -> f16 logits, layout [b][l][16p]
    int p0 = pq * 4;
    #pragma unroll
    for (int q = 0; q < 4; q++){
        int jt = wu * 4 + q;
        int swzj = (jt & 7) << 1;
        const unsigned short* rowp = &x1u[(jt * 16 + lcol) * 68];
        union { bf16x8 v; uint2 u[2]; } b0, b1;
        b0.u[0] = *(const uint2*)&rowp[((k0d)          ^ swzj) * 2];
        b0.u[1] = *(const uint2*)&rowp[((k0d + 2)      ^ swzj) * 2];
        b1.u[0] = *(const uint2*)&rowp[((16 + k0d)     ^ swzj) * 2];
        b1.u[1] = *(const uint2*)&rowp[((16 + k0d + 2) ^ swzj) * 2];
        f32x4 acc = {0.f, 0.f, 0.f, 0.f};
        acc = __builtin_amdgcn_mfma_f32_16x16x32_bf16(aaf0, b0.v, acc, 0, 0, 0);
        acc = __builtin_amdgcn_mfma_f32_16x16x32_bf16(aaf1, b1.v, acc, 0, 0, 0);
        int gx = h * WIDTH + jt * 16 + lcol;
        __half h0 = __float2half(acc[0]), h1v = __float2half(acc[1]);
        __half h2 = __float2half(acc[2]), h3v = __float2half(acc[3]);
        unsigned int u0 = (unsigned int)(*(unsigned short*)&h0)
                        | ((unsigned int)(*(unsigned short*)&h1v) << 16);
        unsigned int u1 = (unsigned int)(*(unsigned short*)&h2)
                        | ((unsigned int)(*(unsigned short*)&h3v) << 16);
        *(uint2*)&logitsH[((size_t)b * HW + gx) * 16 + p0] = make_uint2(u0, u1);
    }
}

// ---------------- K3: Sobel stats, row-based (coalesced float4 + shuffles) ----------------
__global__ __launch_bounds__(256) void k_sobel_stats(const float* __restrict__ ei,
                                                     float* __restrict__ part){
    int ch = blockIdx.x, b = blockIdx.y, t = threadIdx.x;
    int lane = t & 63, w = t >> 6;
    int h = ch * 4 + w;
    int px0 = lane * 4;
    const float* e = ei + (size_t)b * HW;
    int hh0 = (h > 0) ? h - 1 : 0;
    int hh2 = (h < 255) ? h + 1 : 255;
    float rw0 = (h > 0) ? 1.f : 0.f;
    float rw2 = (h < 255) ? 1.f : 0.f;
    float4 v0 = *(const float4*)(e + hh0 * WIDTH + px0);
    float4 v1 = *(const float4*)(e + h   * WIDTH + px0);
    float4 v2 = *(const float4*)(e + hh2 * WIDTH + px0);
    v0.x *= rw0; v0.y *= rw0; v0.z *= rw0; v0.w *= rw0;
    v2.x *= rw2; v2.y *= rw2; v2.z *= rw2; v2.w *= rw2;
    float l0 = __shfl_up(v0.w, 1);   if (lane == 0)  l0 = 0.f;
    float r0 = __shfl_down(v0.x, 1); if (lane == 63) r0 = 0.f;
    float l1 = __shfl_up(v1.w, 1);   if (lane == 0)  l1 = 0.f;
    float r1 = __shfl_down(v1.x, 1); if (lane == 63) r1 = 0.f;
    float l2 = __shfl_up(v2.w, 1);   if (lane == 0)  l2 = 0.f;
    float r2 = __shfl_down(v2.x, 1); if (lane == 63) r2 = 0.f;
    float t0[6]  = {l0, v0.x, v0.y, v0.z, v0.w, r0};
    float m1a[6] = {l1, v1.x, v1.y, v1.z, v1.w, r1};
    float b2a[6] = {l2, v2.x, v2.y, v2.z, v2.w, r2};
    float s1 = 0.f, s2 = 0.f;
    #pragma unroll
    for (int j = 0; j < 4; j++){
        float gx = (t0[j+2] - t0[j]) + 2.f*(m1a[j+2] - m1a[j]) + (b2a[j+2] - b2a[j]);
        float gy = (b2a[j] + 2.f*b2a[j+1] + b2a[j+2]) - (t0[j] + 2.f*t0[j+1] + t0[j+2]);
        float esv = sqrtf(gx*gx + gy*gy + 1e-6f);
        s1 += esv; s2 += esv * esv;
    }
    #pragma unroll
    for (int off = 32; off >= 1; off >>= 1){
        s1 += __shfl_xor(s1, off, 64);
        s2 += __shfl_xor(s2, off, 64);
    }
    __shared__ float rs1[4], rs2[4];
    if (lane == 0){ rs1[w] = s1; rs2[w] = s2; }
    __syncthreads();
    if (t == 0)
        part[(b*64+ch)*2]     = (rs1[0] + rs1[1]) + (rs1[2] + rs1[3]);
    if (t == 1)
        part[(b*64+ch)*2 + 1] = (rs2[0] + rs2[1]) + (rs2[2] + rs2[3]);
}

// ---------------- K4+K5: max-only pass 1, single-exp pass 2, prototype partials ----------------
__global__ __launch_bounds__(256) void k_smproto(
    const unsigned short* __restrict__ logitsH, const float* __restrict__ ei,
    const float* __restrict__ part, const float* __restrict__ proto_orient,
    const float* __restrict__ topo_s, const float* __restrict__ orient_s,
    const float* __restrict__ key,
    float* __restrict__ smpart, float* __restrict__ ppart)
{
    int ch = blockIdx.x, b = blockIdx.y, t = threadIdx.x;
    __shared__ float eit[4][258];
    __shared__ float sstat[3];
    __shared__ float pdl[32];
    __shared__ float Ml[16];
    __shared__ float rm[4][16], rs[4][16];
    __shared__ unsigned int wlds[512][10];

    // ---- pass 0: ei tile + batch stats + proto dirs
    for (int i = t; i < 1024; i += 256){
        int r = i >> 8, c = i & 255;
        int row = 2 * ch - 1 + r;
        eit[r][c + 1] = (row >= 0 && row < 256) ? ei[(size_t)b * HW + row * 256 + c] : 0.f;
    }
    if (t >= 128 && t < 136){
        int q = t - 128;
        eit[q >> 1][(q & 1) * 257] = 0.f;
    }
    if (t < 64){
        float s1 = part[(b*64 + t)*2], s2 = part[(b*64 + t)*2 + 1];
        #pragma unroll
        for (int off = 32; off >= 1; off >>= 1){
            s1 += __shfl_xor(s1, off, 64);
            s2 += __shfl_xor(s2, off, 64);
        }
        if (t == 0){
            float mean = s1 / 65536.f;
            float var = (s2 - 65536.f * mean * mean) / 65535.f;
            var = var > 0.f ? var : 0.f;
            sstat[0] = mean;
            sstat[1] = 1.f / (sqrtf(var) + 1e-5f);
            sstat[2] = 1.f / (mean + 1e-6f);
        }
    } else if (t >= 64 && t < 80){
        int p = t - 64;
        float nx = proto_orient[p*2], ny = proto_orient[p*2+1];
        float n = sqrtf(nx*nx + ny*ny);
        n = n > 1e-12f ? n : 1e-12f;
        pdl[p*2] = nx / n; pdl[p*2+1] = ny / n;
    }
    __syncthreads();
    float mean = sstat[0], rstd = sstat[1], cinv = sstat[2];
    float topo = topo_s[0], orient = orient_s[0];

    // ---- load packed f16 logits for both tokens (kept in regs), compute bias terms
    uint4 pkA0, pkA1, pkB0, pkB1;
    {
        size_t gl0 = ((size_t)b * HW + ch * 512 + t) * 16;
        size_t gl1 = ((size_t)b * HW + ch * 512 + 256 + t) * 16;
        pkA0 = *(const uint4*)&logitsH[gl0];
        pkA1 = *(const uint4*)&logitsH[gl0 + 8];
        pkB0 = *(const uint4*)&logitsH[gl1];
        pkB1 = *(const uint4*)&logitsH[gl1 + 8];
    }
    float ewv[2], oxv[2], oyv[2];
    #pragma unroll
    for (int i = 0; i < 2; i++){
        int hl = i + 1, w = t;
        float vmm = eit[hl-1][w], vm0 = eit[hl-1][w+1], vmp = eit[hl-1][w+2];
        float v0m = eit[hl][w],                          v0p = eit[hl][w+2];
        float vpm = eit[hl+1][w], vp0 = eit[hl+1][w+1], vpp = eit[hl+1][w+2];
        float gx = vmp - vmm + 2.f*(v0p - v0m) + vpp - vpm;
        float gy = vpm + 2.f*vp0 + vpp - vmm - 2.f*vm0 - vmp;
        float denom = gx*gx + gy*gy + 1e-6f;
        float esv = sqrtf(denom);
        float cf = fminf(fmaxf(esv * cinv, 0.f), 3.f);
        ewv[i] = (esv - mean) * rstd;
        oxv[i] = ((gx*gx - gy*gy) / denom) * cf;
        oyv[i] = (2.f * gx * gy / denom) * cf;
    }

    // ---- pass 1: MAX only (no exp). m[16] live, logits recomputed from pk regs.
    float m[16];
    {
        unsigned int wv0[8] = {pkA0.x, pkA0.y, pkA0.z, pkA0.w, pkA1.x, pkA1.y, pkA1.z, pkA1.w};
        unsigned int wv1[8] = {pkB0.x, pkB0.y, pkB0.z, pkB0.w, pkB1.x, pkB1.y, pkB1.z, pkB1.w};
        #pragma unroll
        for (int p = 0; p < 16; p++){
            unsigned int b0 = (p & 1) ? (wv0[p >> 1] >> 16) : (wv0[p >> 1] & 0xffffu);
            unsigned int b1 = (p & 1) ? (wv1[p >> 1] >> 16) : (wv1[p >> 1] & 0xffffu);
            float x0 = h2f(b0) + topo * ewv[0] + orient * (oxv[0]*pdl[p*2] + oyv[0]*pdl[p*2+1]);
            float x1 = h2f(b1) + topo * ewv[1] + orient * (oxv[1]*pdl[p*2] + oyv[1]*pdl[p*2+1]);
            m[p] = fmaxf(x0, x1);
        }
    }
    #pragma unroll
    for (int p = 0; p < 16; p++){
        #pragma unroll
        for (int off = 32; off >= 1; off >>= 1)
            m[p] = fmaxf(m[p], __shfl_xor(m[p], off, 64));
    }
    int wid = t >> 6;
    if ((t & 63) == 0){
        #pragma unroll
        for (int p = 0; p < 16; p++) rm[wid][p] = m[p];
    }
    __syncthreads();
    if (t < 16)
        Ml[t] = fmaxf(fmaxf(rm[0][t], rm[1][t]), fmaxf(rm[2][t], rm[3][t]));
    __syncthreads();

    // ---- pass 2: recompute biased logits, take the ONLY 32 exps, write LDS + sums
    float sthr[16];
    {
        unsigned int wv0[8] = {pkA0.x, pkA0.y, pkA0.z, pkA0.w, pkA1.x, pkA1.y, pkA1.z, pkA1.w};
        unsigned int wv1[8] = {pkB0.x, pkB0.y, pkB0.z, pkB0.w, pkB1.x, pkB1.y, pkB1.z, pkB1.w};
        #pragma unroll
        for (int p2 = 0; p2 < 8; p2++){
            int pa = 2*p2, pb2 = 2*p2 + 1;
            float xa0 = h2f(wv0[p2] & 0xffffu) + topo*ewv[0]
                      + orient*(oxv[0]*pdl[pa*2]  + oyv[0]*pdl[pa*2+1]);
            float xb0 = h2f(wv0[p2] >> 16) + topo*ewv[0]
                      + orient*(oxv[0]*pdl[pb2*2] + oyv[0]*pdl[pb2*2+1]);
            float xa1 = h2f(wv1[p2] & 0xffffu) + topo*ewv[1]
                      + orient*(oxv[1]*pdl[pa*2]  + oyv[1]*pdl[pa*2+1]);
            float xb1 = h2f(wv1[p2] >> 16) + topo*ewv[1]
                      + orient*(oxv[1]*pdl[pb2*2] + oyv[1]*pdl[pb2*2+1]);
            float ea0 = __expf(xa0 - Ml[pa]);
            float eb0 = __expf(xb0 - Ml[pb2]);
            float ea1 = __expf(xa1 - Ml[pa]);
            float eb1 = __expf(xb1 - Ml[pb2]);
            sthr[pa]  = ea0 + ea1;
            sthr[pb2] = eb0 + eb1;
            wlds[t][p2]       = f2bf(ea0) | (f2bf(eb0) << 16);
            wlds[256 + t][p2] = f2bf(ea1) | (f2bf(eb1) << 16);
        }
    }
    #pragma unroll
    for (int p = 0; p < 16; p++){
        #pragma unroll
        for (int off = 32; off >= 1; off >>= 1)
            sthr[p] += __shfl_xor(sthr[p], off, 64);
    }
    if ((t & 63) == 0){
        #pragma unroll
        for (int p = 0; p < 16; p++) rs[wid][p] = sthr[p];
    }
    __syncthreads();
    if (t < 16){
        smpart[((b*16 + t)*128 + ch)*2]     = Ml[t];
        smpart[((b*16 + t)*128 + ch)*2 + 1] = (rs[0][t] + rs[1][t]) + (rs[2][t] + rs[3][t]);
    }

    // ---- pass 3: coalesced key stream; lane = (token-phase g, c-slice cg), all 16 p
    int w = t >> 6, lane = t & 63, cg = lane & 15, g = lane >> 4;
    const float4* kp = (const float4*)key + ((size_t)b * HW + ch * 512 + w * 128) * 16;
    float acc[16][4];
    #pragma unroll
    for (int p = 0; p < 16; p++)
        #pragma unroll
        for (int i = 0; i < 4; i++) acc[p][i] = 0.f;
    #pragma unroll 4
    for (int blk = 0; blk < 32; blk++){
        int tok = blk * 4 + g;
        float4 kv = kp[tok * 16 + cg];
        const unsigned int* wp = &wlds[w * 128 + tok][0];
        uint2 q0 = *(const uint2*)&wp[0];
        uint2 q1 = *(const uint2*)&wp[2];
        uint2 q2 = *(const uint2*)&wp[4];
        uint2 q3 = *(const uint2*)&wp[6];
        unsigned int ww[8] = {q0.x, q0.y, q1.x, q1.y, q2.x, q2.y, q3.x, q3.y};
        #pragma unroll
        for (int p2 = 0; p2 < 8; p2++){
            float wa = bfbits2f(ww[p2] & 0xffffu);
            float wb = bfbits2f(ww[p2] >> 16);
            int pa = 2*p2, pb2 = 2*p2 + 1;
            acc[pa][0] = fmaf(wa, kv.x, acc[pa][0]);
            acc[pa][1] = fmaf(wa, kv.y, acc[pa][1]);
            acc[pa][2] = fmaf(wa, kv.z, acc[pa][2]);
            acc[pa][3] = fmaf(wa, kv.w, acc[pa][3]);
            acc[pb2][0] = fmaf(wb, kv.x, acc[pb2][0]);
            acc[pb2][1] = fmaf(wb, kv.y, acc[pb2][1]);
            acc[pb2][2] = fmaf(wb, kv.z, acc[pb2][2]);
            acc[pb2][3] = fmaf(wb, kv.w, acc[pb2][3]);
        }
    }
    #pragma unroll
    for (int p = 0; p < 16; p++)
        #pragma unroll
        for (int i = 0; i < 4; i++){
            acc[p][i] += __shfl_xor(acc[p][i], 16, 64);
            acc[p][i] += __shfl_xor(acc[p][i], 32, 64);
        }
    __syncthreads();
    float (*red)[16][68] = (float (*)[16][68])wlds;
    if (g == 0){
        #pragma unroll
        for (int p = 0; p < 16; p++)
            *(float4*)&red[w][p][cg*4] =
                make_float4(acc[p][0], acc[p][1], acc[p][2], acc[p][3]);
    }
    __syncthreads();
    size_t obase = ((size_t)(b * 128 + ch)) * 1024;
    for (int idx = t; idx < 1024; idx += 256){
        int p = idx >> 6, c = idx & 63;
        ppart[obase + idx] = red[0][p][c] + red[1][p][c] + red[2][p][c] + red[3][p][c];
    }
}

// ---------------- K7: flv + ppart reduce + gate MLPs + sigmoid + LayerNorm ----------------
__global__ __launch_bounds__(256) void k_gate(
    const float* __restrict__ smpart, const float* __restrict__ ppart,
    const float* __restrict__ query,
    const float* __restrict__ w1, const float* __restrict__ bb1,
    const float* __restrict__ w2, const float* __restrict__ bb2,
    const float* __restrict__ gw1, const float* __restrict__ gb1,
    const float* __restrict__ gw2, const float* __restrict__ gb2,
    const float* __restrict__ lng, const float* __restrict__ lnb,
    float* __restrict__ out)
{
    __shared__ float z[16][64], h1[16][64], loc[16][64], g[64], hg[64], glb[64];
    __shared__ float flv[16][128];
    int b = blockIdx.x, t = threadIdx.x;
    {
        int p = t >> 4, j = t & 15;
        const float* sp = smpart + ((size_t)(b*16 + p)) * 256;
        float M = -1e30f, S = 0.f;
        #pragma unroll
        for (int k = 0; k < 8; k++){
            int ch = j*8 + k;
            float mw = sp[ch*2], sw = sp[ch*2 + 1];
            float mn = fmaxf(M, mw);
            S = S * __expf(M - mn) + sw * __expf(mw - mn);
            M = mn;
        }
        #pragma unroll
        for (int off = 8; off >= 1; off >>= 1){
            float m2 = __shfl_xor(M, off, 64);
            float s2 = __shfl_xor(S, off, 64);
            float mn = fmaxf(M, m2);
            S = S * __expf(M - mn) + s2 * __expf(m2 - mn);
            M = mn;
        }
        float rinv = 1.f / S;
        #pragma unroll
        for (int k = 0; k < 8; k++){
            int ch = j*8 + k;
            flv[p][ch] = __expf(sp[ch*2] - M) * rinv;
        }
    }
    __syncthreads();
    for (int idx = t; idx < 1024; idx += 256){
        int p = idx >> 6;
        const float* pp = ppart + (size_t)b * 128 * 1024 + idx;
        float sacc = 0.f;
        #pragma unroll 8
        for (int ch = 0; ch < 128; ch++) sacc += flv[p][ch] * pp[(size_t)ch * 1024];
        z[p][idx & 63] = sacc + query[b * 1024 + idx];
    }
    __syncthreads();
    for (int idx = t; idx < 1024; idx += 256){
        int p = idx >> 6, j = idx & 63;
        float acc = bb1[j];
        for (int i = 0; i < 64; i++) acc += z[p][i] * w1[j * 64 + i];
        h1[p][j] = relu_f(acc);
    }
    if (t < 64){
        float sg = 0.f;
        for (int p = 0; p < 16; p++) sg += z[p][t];
        g[t] = sg * (1.f / 16.f);
    }
    __syncthreads();
    for (int idx = t; idx < 1024; idx += 256){
        int p = idx >> 6, k = idx & 63;
        float acc = bb2[k];
        for (int j = 0; j < 64; j++) acc += h1[p][j] * w2[k * 64 + j];
        loc[p][k] = acc;
    }
    if (t < 64){
        float acc = gb1[t];
        for (int i = 0; i < 64; i++) acc += g[i] * gw1[t * 64 + i];
        hg[t] = relu_f(acc);
    }
    __syncthreads();
    if (t < 64){
        float acc = gb2[t];
        for (int j = 0; j < 64; j++) acc += hg[j] * gw2[t * 64 + j];
        glb[t] = acc;
    }
    __syncthreads();
    for (int idx = t; idx < 1024; idx += 256){
        int p = idx >> 6, c = idx & 63;
        float a = loc[p][c] + glb[c];
        float sg = 1.f / (1.f + expf(-a));
        float q = query[b * 1024 + idx];
        h1[p][c] = q * sg + q;
    }
    __syncthreads();
    if (t < 16){
        int p = t;
        float mu = 0.f;
        for (int c = 0; c < 64; c++) mu += h1[p][c];
        mu *= (1.f / 64.f);
        float var = 0.f;
        for (int c = 0; c < 64; c++){ float d = h1[p][c] - mu; var += d * d; }
        var *= (1.f / 64.f);
        float rstd = rsqrtf(var + 1e-5f);
        for (int c = 0; c < 64; c++)
            out[b * 1024 + p * 64 + c] = (h1[p][c] - mu) * rstd * lng[c] + lnb[c];
    }
}

extern "C" void kernel_launch(void* const* d_in, const int* in_sizes, int n_in,
                              void* d_out, int out_size, void* d_ws, size_t ws_size,
                              hipStream_t stream){
    (void)in_sizes; (void)n_in; (void)out_size; (void)ws_size;
    const float* feat   = (const float*)d_in[0];
    const float* query  = (const float*)d_in[1];
    const float* key    = (const float*)d_in[2];
    const float* dw_w   = (const float*)d_in[3];
    const float* bn1_g  = (const float*)d_in[4];
    const float* bn1_b  = (const float*)d_in[5];
    const float* bn1_m  = (const float*)d_in[6];
    const float* bn1_v  = (const float*)d_in[7];
    const float* pw_w   = (const float*)d_in[8];
    const float* bn2_g  = (const float*)d_in[9];
    const float* bn2_b  = (const float*)d_in[10];
    const float* bn2_m  = (const float*)d_in[11];
    const float* bn2_v  = (const float*)d_in[12];
    const float* aff_w  = (const float*)d_in[13];
    const float* loc_w1 = (const float*)d_in[14];
    const float* loc_b1 = (const float*)d_in[15];
    const float* loc_w2 = (const float*)d_in[16];
    const float* loc_b2 = (const float*)d_in[17];
    const float* glb_w1 = (const float*)d_in[18];
    const float* glb_b1 = (const float*)d_in[19];
    const float* glb_w2 = (const float*)d_in[20];
    const float* glb_b2 = (const float*)d_in[21];
    const float* ln_g   = (const float*)d_in[22];
    const float* ln_b   = (const float*)d_in[23];
    const float* topo   = (const float*)d_in[24];
    const float* orient = (const float*)d_in[25];
    const float* proto_orient = (const float*)d_in[26];
    float* out = (float*)d_out;
    float* ws  = (float*)d_ws;

    float* ei      = ws;                                       // 524288 f
    unsigned short* logitsH = (unsigned short*)(ws + 1048576); // 8,388,608 ushort
    float* ppart   = ws + 5242880;                             // 1,048,576 f
    float* k3part  = ws + 6291456;                             // 1024
    float* smpart  = ws + 6292480;                             // 32768
    float* scsh    = ws + 6333440;                             // 256
    unsigned short* pwA  = (unsigned short*)(ws + 6333696);    // 4096 ushort
    unsigned short* affA = (unsigned short*)(ws + 6335744);    // 1024 ushort

    k_prep<<<1, 256, 0, stream>>>(pw_w, aff_w, bn1_g, bn1_b, bn1_m, bn1_v,
                                  bn2_g, bn2_b, bn2_m, bn2_v, scsh, pwA, affA);
    k_conv_aff<<<2048, 256, 0, stream>>>(feat, dw_w, scsh, pwA, affA, logitsH, ei);
    k_sobel_stats<<<dim3(64, 8), 256, 0, stream>>>(ei, k3part);
    k_smproto<<<dim3(128, 8), 256, 0, stream>>>(logitsH, ei, k3part, proto_orient,
                                                topo, orient, key, smpart, ppart);
    k_gate<<<8, 256, 0, stream>>>(smpart, ppart, query, loc_w1, loc_b1, loc_w2, loc_b2,
                                  glb_w1, glb_b1, glb_w2, glb_b2, ln_g, ln_b, out);
}

// Round 13
// 123.651 us; speedup vs baseline: 1.1419x; 1.1419x over previous
//
#include <hip/hip_runtime.h>
#include <hip/hip_fp16.h>
#include <math.h>

#define HW     65536
#define WIDTH  256
#define HEIGHT 256

typedef __attribute__((ext_vector_type(8))) short bf16x8;
typedef __attribute__((ext_vector_type(4))) float f32x4;

__device__ __forceinline__ float relu_f(float x){ return x > 0.f ? x : 0.f; }
__device__ __forceinline__ unsigned int f2bf(float x){
    union { float f; unsigned int u; } v; v.f = x;
    unsigned int r = v.u + 0x7fffu + ((v.u >> 16) & 1u);   // RNE
    return r >> 16;
}
__device__ __forceinline__ float bfbits2f(unsigned int lo16){
    union { unsigned int u; float f; } v; v.u = lo16 << 16; return v.f;
}
__device__ __forceinline__ float h2f(unsigned int bits16){
    __half h = *(__half*)&bits16; return __half2float(h);
}

// ---------------- K0: prep — fold BN, pack MFMA A-fragments ----------------
__global__ void k_prep(const float* __restrict__ pw_w, const float* __restrict__ aff_w,
                       const float* __restrict__ g1, const float* __restrict__ b1,
                       const float* __restrict__ m1, const float* __restrict__ v1,
                       const float* __restrict__ g2, const float* __restrict__ b2,
                       const float* __restrict__ m2, const float* __restrict__ v2,
                       float* __restrict__ scsh, unsigned short* __restrict__ pwA,
                       unsigned short* __restrict__ affA){
    int t = threadIdx.x;
    for (int i = t; i < 4096; i += 256){
        int e = i & 7, l = (i >> 3) & 63, ks = (i >> 9) & 1, ct = i >> 10;
        int co = ct * 16 + (l & 15);
        int ci = ks * 32 + (l >> 4) * 8 + e;
        pwA[i] = (unsigned short)f2bf(pw_w[co * 64 + ci]);
    }
    for (int i = t; i < 1024; i += 256){
        int e = i & 7, l = (i >> 3) & 63, ks = i >> 9;
        int p = l & 15, k = ks * 32 + (l >> 4) * 8 + e;
        affA[i] = (unsigned short)f2bf(aff_w[p * 64 + k]);
    }
    if (t < 64){
        float s = g1[t] * rsqrtf(v1[t] + 1e-5f);
        scsh[t]       = s;
        scsh[64 + t]  = b1[t] - m1[t] * s;
        float s2 = g2[t] * rsqrtf(v2[t] + 1e-5f);
        scsh[128 + t] = s2;
        scsh[192 + t] = b2[t] - m2[t] * s2;
    }
}

// ---------------- K2: full-row dw3x3 (pipelined) -> MFMA pw -> MFMA affinity -> f16 logits ----------------
__global__ __launch_bounds__(256, 4) void k_conv_aff(
    const float* __restrict__ feat, const float* __restrict__ dw_w,
    const float* __restrict__ scsh, const unsigned short* __restrict__ pwA,
    const unsigned short* __restrict__ affA,
    unsigned short* __restrict__ logitsH, float* __restrict__ ei)
{
    __shared__ unsigned short x1u[256 * 68];
    __shared__ float eibuf[4][256];
    int t = threadIdx.x;
    int lane = t & 63;
    int wu = __builtin_amdgcn_readfirstlane(t >> 6);
    int orig = blockIdx.x;
    int flat = (orig & 7) * 256 + (orig >> 3);   // XCD-bijective (2048 = 8*256)
    int b = flat >> 8, h = flat & 255;

    const bf16x8* pwA8 = (const bf16x8*)pwA;
    bf16x8 apw0 = pwA8[(wu * 2 + 0) * 64 + lane];
    bf16x8 apw1 = pwA8[(wu * 2 + 1) * 64 + lane];
    const bf16x8* affA8 = (const bf16x8*)affA;
    bf16x8 aaf0 = affA8[lane];
    bf16x8 aaf1 = affA8[64 + lane];
    int lcol = lane & 15, pq = lane >> 4;
    int cb = wu * 16 + pq * 4;
    float4 sc2v = *(const float4*)(scsh + 128 + cb);
    float4 sh2v = *(const float4*)(scsh + 192 + cb);

    // ---- phase A: depthwise 3x3, 4 px/lane, software-pipelined ci-pair loop
    int px0 = lane * 4;
    const float* fb = feat + (size_t)b * 64 * HW;
    int hh0 = (h > 0) ? h - 1 : 0;
    int hh2 = (h < 255) ? h + 1 : 255;
    float rw0 = (h > 0) ? 1.f : 0.f;
    float rw2 = (h < 255) ? 1.f : 0.f;
    int   roff0 = hh0 * WIDTH, roff1 = h * WIDTH, roff2 = hh2 * WIDTH;
    float mx = 0.f, my = 0.f, mz = 0.f, mw = 0.f;
    int swz = ((lane >> 2) & 7) << 1;

    float4 cur0[3], cur1[3], nxt0[3], nxt1[3];
    {
        const float* p0 = fb + (size_t)(wu * 16) * HW + px0;
        const float* p1 = p0 + HW;
        cur0[0] = *(const float4*)(p0 + roff0);
        cur0[1] = *(const float4*)(p0 + roff1);
        cur0[2] = *(const float4*)(p0 + roff2);
        cur1[0] = *(const float4*)(p1 + roff0);
        cur1[1] = *(const float4*)(p1 + roff1);
        cur1[2] = *(const float4*)(p1 + roff2);
    }
    #pragma unroll
    for (int cp = 0; cp < 8; cp++){
        int ci0 = wu * 16 + cp * 2;
        int ci1 = ci0 + 1;
        if (cp < 7){
            const float* p0 = fb + (size_t)(ci0 + 2) * HW + px0;
            const float* p1 = p0 + HW;
            nxt0[0] = *(const float4*)(p0 + roff0);
            nxt0[1] = *(const float4*)(p0 + roff1);
            nxt0[2] = *(const float4*)(p0 + roff2);
            nxt1[0] = *(const float4*)(p1 + roff0);
            nxt1[1] = *(const float4*)(p1 + roff1);
            nxt1[2] = *(const float4*)(p1 + roff2);
        }
        float a00=0.f,a01=0.f,a02=0.f,a03=0.f, a10=0.f,a11=0.f,a12=0.f,a13=0.f;
        #pragma unroll
        for (int r = 0; r < 3; r++){
            float rwf = (r == 0) ? rw0 : ((r == 1) ? 1.f : rw2);
            float4 v0 = cur0[r];
            float4 v1 = cur1[r];
            float w00 = dw_w[ci0*9 + r*3 + 0] * rwf;
            float w01 = dw_w[ci0*9 + r*3 + 1] * rwf;
            float w02 = dw_w[ci0*9 + r*3 + 2] * rwf;
            float w10 = dw_w[ci1*9 + r*3 + 0] * rwf;
            float w11 = dw_w[ci1*9 + r*3 + 1] * rwf;
            float w12 = dw_w[ci1*9 + r*3 + 2] * rwf;
            float lf0 = __shfl_up(v0.w, 1);  if (lane == 0)  lf0 = 0.f;
            float rt0 = __shfl_down(v0.x, 1); if (lane == 63) rt0 = 0.f;
            float lf1 = __shfl_up(v1.w, 1);  if (lane == 0)  lf1 = 0.f;
            float rt1 = __shfl_down(v1.x, 1); if (lane == 63) rt1 = 0.f;
            a00 += lf0*w00 + v0.x*w01 + v0.y*w02;
            a01 += v0.x*w00 + v0.y*w01 + v0.z*w02;
            a02 += v0.y*w00 + v0.z*w01 + v0.w*w02;
            a03 += v0.z*w00 + v0.w*w01 + rt0*w02;
            a10 += lf1*w10 + v1.x*w11 + v1.y*w12;
            a11 += v1.x*w10 + v1.y*w11 + v1.z*w12;
            a12 += v1.y*w10 + v1.z*w11 + v1.w*w12;
            a13 += v1.z*w10 + v1.w*w11 + rt1*w12;
            if (r == 1){
                mx += v0.x + v1.x; my += v0.y + v1.y;
                mz += v0.z + v1.z; mw += v0.w + v1.w;
            }
        }
        float s0 = scsh[ci0], o0 = scsh[64 + ci0];
        float s1 = scsh[ci1], o1 = scsh[64 + ci1];
        int dwi = ((wu * 8 + cp) ^ swz) * 2;
        unsigned int pk0 = f2bf(relu_f(fmaf(a00,s0,o0))) | (f2bf(relu_f(fmaf(a10,s1,o1))) << 16);
        unsigned int pk1 = f2bf(relu_f(fmaf(a01,s0,o0))) | (f2bf(relu_f(fmaf(a11,s1,o1))) << 16);
        unsigned int pk2 = f2bf(relu_f(fmaf(a02,s0,o0))) | (f2bf(relu_f(fmaf(a12,s1,o1))) << 16);
        unsigned int pk3 = f2bf(relu_f(fmaf(a03,s0,o0))) | (f2bf(relu_f(fmaf(a13,s1,o1))) << 16);
        *(unsigned int*)&x1u[(px0 + 0) * 68 + dwi] = pk0;
        *(unsigned int*)&x1u[(px0 + 1) * 68 + dwi] = pk1;
        *(unsigned int*)&x1u[(px0 + 2) * 68 + dwi] = pk2;
        *(unsigned int*)&x1u[(px0 + 3) * 68 + dwi] = pk3;
        #pragma unroll
        for (int r = 0; r < 3; r++){ cur0[r] = nxt0[r]; cur1[r] = nxt1[r]; }
    }
    *(float4*)&eibuf[wu][px0] = make_float4(mx, my, mz, mw);
    __syncthreads();
    {
        float m = (eibuf[0][t] + eibuf[1][t]) + (eibuf[2][t] + eibuf[3][t]);
        ei[(size_t)b * HW + h * WIDTH + t] = m * (1.f / 64.f);
    }

    // ---- phase B
    int k0d = pq * 4;
    #pragma unroll
    for (int half = 0; half < 2; half++){
        f32x4 accB[8];
        #pragma unroll
        for (int q = 0; q < 8; q++){
            int jt = half * 8 + q;
            int swzj = (jt & 7) << 1;
            const unsigned short* rowp = &x1u[(jt * 16 + lcol) * 68];
            union { bf16x8 v; uint2 u[2]; } b0, b1;
            b0.u[0] = *(const uint2*)&rowp[((k0d)          ^ swzj) * 2];
            b0.u[1] = *(const uint2*)&rowp[((k0d + 2)      ^ swzj) * 2];
            b1.u[0] = *(const uint2*)&rowp[((16 + k0d)     ^ swzj) * 2];
            b1.u[1] = *(const uint2*)&rowp[((16 + k0d + 2) ^ swzj) * 2];
            f32x4 acc = {0.f, 0.f, 0.f, 0.f};
            acc = __builtin_amdgcn_mfma_f32_16x16x32_bf16(apw0, b0.v, acc, 0, 0, 0);
            acc = __builtin_amdgcn_mfma_f32_16x16x32_bf16(apw1, b1.v, acc, 0, 0, 0);
            accB[q] = acc;
        }
        __syncthreads();
        #pragma unroll
        for (int q = 0; q < 8; q++){
            int jt = half * 8 + q;
            int swzj = (jt & 7) << 1;
            f32x4 acc = accB[q];
            unsigned int y0 = f2bf(relu_f(fmaf(acc[0], sc2v.x, sh2v.x)))
                            | (f2bf(relu_f(fmaf(acc[1], sc2v.y, sh2v.y))) << 16);
            unsigned int y1 = f2bf(relu_f(fmaf(acc[2], sc2v.z, sh2v.z)))
                            | (f2bf(relu_f(fmaf(acc[3], sc2v.w, sh2v.w))) << 16);
            int D = (wu * 8 + pq * 2) ^ swzj;
            *(uint2*)&x1u[(jt * 16 + lcol) * 68 + D * 2] = make_uint2(y0, y1);
        }
    }
    __syncthreads();

    // ---- phase C: affinity GEMM -> f16 logits, layout [b][l][16p]
    int p0 = pq * 4;
    #pragma unroll
    for (int q = 0; q < 4; q++){
        int jt = wu * 4 + q;
        int swzj = (jt & 7) << 1;
        const unsigned short* rowp = &x1u[(jt * 16 + lcol) * 68];
        union { bf16x8 v; uint2 u[2]; } b0, b1;
        b0.u[0] = *(const uint2*)&rowp[((k0d)          ^ swzj) * 2];
        b0.u[1] = *(const uint2*)&rowp[((k0d + 2)      ^ swzj) * 2];
        b1.u[0] = *(const uint2*)&rowp[((16 + k0d)     ^ swzj) * 2];
        b1.u[1] = *(const uint2*)&rowp[((16 + k0d + 2) ^ swzj) * 2];
        f32x4 acc = {0.f, 0.f, 0.f, 0.f};
        acc = __builtin_amdgcn_mfma_f32_16x16x32_bf16(aaf0, b0.v, acc, 0, 0, 0);
        acc = __builtin_amdgcn_mfma_f32_16x16x32_bf16(aaf1, b1.v, acc, 0, 0, 0);
        int gx = h * WIDTH + jt * 16 + lcol;
        __half h0 = __float2half(acc[0]), h1v = __float2half(acc[1]);
        __half h2 = __float2half(acc[2]), h3v = __float2half(acc[3]);
        unsigned int u0 = (unsigned int)(*(unsigned short*)&h0)
                        | ((unsigned int)(*(unsigned short*)&h1v) << 16);
        unsigned int u1 = (unsigned int)(*(unsigned short*)&h2)
                        | ((unsigned int)(*(unsigned short*)&h3v) << 16);
        *(uint2*)&logitsH[((size_t)b * HW + gx) * 16 + p0] = make_uint2(u0, u1);
    }
}

// ---------------- K3: Sobel stats, row-based (coalesced float4 + shuffles) ----------------
__global__ __launch_bounds__(256) void k_sobel_stats(const float* __restrict__ ei,
                                                     float* __restrict__ part){
    int ch = blockIdx.x, b = blockIdx.y, t = threadIdx.x;
    int lane = t & 63, w = t >> 6;
    int h = ch * 4 + w;
    int px0 = lane * 4;
    const float* e = ei + (size_t)b * HW;
    int hh0 = (h > 0) ? h - 1 : 0;
    int hh2 = (h < 255) ? h + 1 : 255;
    float rw0 = (h > 0) ? 1.f : 0.f;
    float rw2 = (h < 255) ? 1.f : 0.f;
    float4 v0 = *(const float4*)(e + hh0 * WIDTH + px0);
    float4 v1 = *(const float4*)(e + h   * WIDTH + px0);
    float4 v2 = *(const float4*)(e + hh2 * WIDTH + px0);
    v0.x *= rw0; v0.y *= rw0; v0.z *= rw0; v0.w *= rw0;
    v2.x *= rw2; v2.y *= rw2; v2.z *= rw2; v2.w *= rw2;
    float l0 = __shfl_up(v0.w, 1);   if (lane == 0)  l0 = 0.f;
    float r0 = __shfl_down(v0.x, 1); if (lane == 63) r0 = 0.f;
    float l1 = __shfl_up(v1.w, 1);   if (lane == 0)  l1 = 0.f;
    float r1 = __shfl_down(v1.x, 1); if (lane == 63) r1 = 0.f;
    float l2 = __shfl_up(v2.w, 1);   if (lane == 0)  l2 = 0.f;
    float r2 = __shfl_down(v2.x, 1); if (lane == 63) r2 = 0.f;
    float t0[6]  = {l0, v0.x, v0.y, v0.z, v0.w, r0};
    float m1a[6] = {l1, v1.x, v1.y, v1.z, v1.w, r1};
    float b2a[6] = {l2, v2.x, v2.y, v2.z, v2.w, r2};
    float s1 = 0.f, s2 = 0.f;
    #pragma unroll
    for (int j = 0; j < 4; j++){
        float gx = (t0[j+2] - t0[j]) + 2.f*(m1a[j+2] - m1a[j]) + (b2a[j+2] - b2a[j]);
        float gy = (b2a[j] + 2.f*b2a[j+1] + b2a[j+2]) - (t0[j] + 2.f*t0[j+1] + t0[j+2]);
        float esv = sqrtf(gx*gx + gy*gy + 1e-6f);
        s1 += esv; s2 += esv * esv;
    }
    #pragma unroll
    for (int off = 32; off >= 1; off >>= 1){
        s1 += __shfl_xor(s1, off, 64);
        s2 += __shfl_xor(s2, off, 64);
    }
    __shared__ float rs1[4], rs2[4];
    if (lane == 0){ rs1[w] = s1; rs2[w] = s2; }
    __syncthreads();
    if (t == 0)
        part[(b*64+ch)*2]     = (rs1[0] + rs1[1]) + (rs1[2] + rs1[3]);
    if (t == 1)
        part[(b*64+ch)*2 + 1] = (rs2[0] + rs2[1]) + (rs2[2] + rs2[3]);
}

// ---------------- K4+K5: max-only pass 1, single-exp pass 2, prototype partials ----------------
__global__ __launch_bounds__(256) void k_smproto(
    const unsigned short* __restrict__ logitsH, const float* __restrict__ ei,
    const float* __restrict__ part, const float* __restrict__ proto_orient,
    const float* __restrict__ topo_s, const float* __restrict__ orient_s,
    const float* __restrict__ key,
    float* __restrict__ smpart, float* __restrict__ ppart)
{
    int ch = blockIdx.x, b = blockIdx.y, t = threadIdx.x;
    __shared__ float eit[4][258];
    __shared__ float sstat[3];
    __shared__ float pdl[32];
    __shared__ float Ml[16];
    __shared__ float rm[4][16], rs[4][16];
    __shared__ unsigned int wlds[512][10];

    // ---- pass 0: ei tile + batch stats + proto dirs
    for (int i = t; i < 1024; i += 256){
        int r = i >> 8, c = i & 255;
        int row = 2 * ch - 1 + r;
        eit[r][c + 1] = (row >= 0 && row < 256) ? ei[(size_t)b * HW + row * 256 + c] : 0.f;
    }
    if (t >= 128 && t < 136){
        int q = t - 128;
        eit[q >> 1][(q & 1) * 257] = 0.f;
    }
    if (t < 64){
        float s1 = part[(b*64 + t)*2], s2 = part[(b*64 + t)*2 + 1];
        #pragma unroll
        for (int off = 32; off >= 1; off >>= 1){
            s1 += __shfl_xor(s1, off, 64);
            s2 += __shfl_xor(s2, off, 64);
        }
        if (t == 0){
            float mean = s1 / 65536.f;
            float var = (s2 - 65536.f * mean * mean) / 65535.f;
            var = var > 0.f ? var : 0.f;
            sstat[0] = mean;
            sstat[1] = 1.f / (sqrtf(var) + 1e-5f);
            sstat[2] = 1.f / (mean + 1e-6f);
        }
    } else if (t >= 64 && t < 80){
        int p = t - 64;
        float nx = proto_orient[p*2], ny = proto_orient[p*2+1];
        float n = sqrtf(nx*nx + ny*ny);
        n = n > 1e-12f ? n : 1e-12f;
        pdl[p*2] = nx / n; pdl[p*2+1] = ny / n;
    }
    __syncthreads();
    float mean = sstat[0], rstd = sstat[1], cinv = sstat[2];
    float topo = topo_s[0], orient = orient_s[0];

    // ---- load packed f16 logits (regs) + bias terms
    uint4 pkA0, pkA1, pkB0, pkB1;
    {
        size_t gl0 = ((size_t)b * HW + ch * 512 + t) * 16;
        size_t gl1 = ((size_t)b * HW + ch * 512 + 256 + t) * 16;
        pkA0 = *(const uint4*)&logitsH[gl0];
        pkA1 = *(const uint4*)&logitsH[gl0 + 8];
        pkB0 = *(const uint4*)&logitsH[gl1];
        pkB1 = *(const uint4*)&logitsH[gl1 + 8];
    }
    float ewv[2], oxv[2], oyv[2];
    #pragma unroll
    for (int i = 0; i < 2; i++){
        int hl = i + 1, w = t;
        float vmm = eit[hl-1][w], vm0 = eit[hl-1][w+1], vmp = eit[hl-1][w+2];
        float v0m = eit[hl][w],                          v0p = eit[hl][w+2];
        float vpm = eit[hl+1][w], vp0 = eit[hl+1][w+1], vpp = eit[hl+1][w+2];
        float gx = vmp - vmm + 2.f*(v0p - v0m) + vpp - vpm;
        float gy = vpm + 2.f*vp0 + vpp - vmm - 2.f*vm0 - vmp;
        float denom = gx*gx + gy*gy + 1e-6f;
        float esv = sqrtf(denom);
        float cf = fminf(fmaxf(esv * cinv, 0.f), 3.f);
        ewv[i] = (esv - mean) * rstd;
        oxv[i] = ((gx*gx - gy*gy) / denom) * cf;
        oyv[i] = (2.f * gx * gy / denom) * cf;
    }

    // ---- pass 1: MAX only (no exp)
    float m[16];
    {
        unsigned int wv0[8] = {pkA0.x, pkA0.y, pkA0.z, pkA0.w, pkA1.x, pkA1.y, pkA1.z, pkA1.w};
        unsigned int wv1[8] = {pkB0.x, pkB0.y, pkB0.z, pkB0.w, pkB1.x, pkB1.y, pkB1.z, pkB1.w};
        #pragma unroll
        for (int p = 0; p < 16; p++){
            unsigned int b0 = (p & 1) ? (wv0[p >> 1] >> 16) : (wv0[p >> 1] & 0xffffu);
            unsigned int b1 = (p & 1) ? (wv1[p >> 1] >> 16) : (wv1[p >> 1] & 0xffffu);
            float x0 = h2f(b0) + topo * ewv[0] + orient * (oxv[0]*pdl[p*2] + oyv[0]*pdl[p*2+1]);
            float x1 = h2f(b1) + topo * ewv[1] + orient * (oxv[1]*pdl[p*2] + oyv[1]*pdl[p*2+1]);
            m[p] = fmaxf(x0, x1);
        }
    }
    #pragma unroll
    for (int p = 0; p < 16; p++){
        #pragma unroll
        for (int off = 32; off >= 1; off >>= 1)
            m[p] = fmaxf(m[p], __shfl_xor(m[p], off, 64));
    }
    int wid = t >> 6;
    if ((t & 63) == 0){
        #pragma unroll
        for (int p = 0; p < 16; p++) rm[wid][p] = m[p];
    }
    __syncthreads();
    if (t < 16)
        Ml[t] = fmaxf(fmaxf(rm[0][t], rm[1][t]), fmaxf(rm[2][t], rm[3][t]));
    __syncthreads();

    // ---- pass 2: recompute biased logits, the only 32 exps, write LDS + sums
    float sthr[16];
    {
        unsigned int wv0[8] = {pkA0.x, pkA0.y, pkA0.z, pkA0.w, pkA1.x, pkA1.y, pkA1.z, pkA1.w};
        unsigned int wv1[8] = {pkB0.x, pkB0.y, pkB0.z, pkB0.w, pkB1.x, pkB1.y, pkB1.z, pkB1.w};
        #pragma unroll
        for (int p2 = 0; p2 < 8; p2++){
            int pa = 2*p2, pb2 = 2*p2 + 1;
            float xa0 = h2f(wv0[p2] & 0xffffu) + topo*ewv[0]
                      + orient*(oxv[0]*pdl[pa*2]  + oyv[0]*pdl[pa*2+1]);
            float xb0 = h2f(wv0[p2] >> 16) + topo*ewv[0]
                      + orient*(oxv[0]*pdl[pb2*2] + oyv[0]*pdl[pb2*2+1]);
            float xa1 = h2f(wv1[p2] & 0xffffu) + topo*ewv[1]
                      + orient*(oxv[1]*pdl[pa*2]  + oyv[1]*pdl[pa*2+1]);
            float xb1 = h2f(wv1[p2] >> 16) + topo*ewv[1]
                      + orient*(oxv[1]*pdl[pb2*2] + oyv[1]*pdl[pb2*2+1]);
            float ea0 = __expf(xa0 - Ml[pa]);
            float eb0 = __expf(xb0 - Ml[pb2]);
            float ea1 = __expf(xa1 - Ml[pa]);
            float eb1 = __expf(xb1 - Ml[pb2]);
            sthr[pa]  = ea0 + ea1;
            sthr[pb2] = eb0 + eb1;
            wlds[t][p2]       = f2bf(ea0) | (f2bf(eb0) << 16);
            wlds[256 + t][p2] = f2bf(ea1) | (f2bf(eb1) << 16);
        }
    }
    #pragma unroll
    for (int p = 0; p < 16; p++){
        #pragma unroll
        for (int off = 32; off >= 1; off >>= 1)
            sthr[p] += __shfl_xor(sthr[p], off, 64);
    }
    if ((t & 63) == 0){
        #pragma unroll
        for (int p = 0; p < 16; p++) rs[wid][p] = sthr[p];
    }
    __syncthreads();
    if (t < 16){
        smpart[((b*16 + t)*128 + ch)*2]     = Ml[t];
        smpart[((b*16 + t)*128 + ch)*2 + 1] = (rs[0][t] + rs[1][t]) + (rs[2][t] + rs[3][t]);
    }

    // ---- pass 3: coalesced key stream; lane = (token-phase g, c-slice cg), all 16 p
    int w = t >> 6, lane = t & 63, cg = lane & 15, g = lane >> 4;
    const float4* kp = (const float4*)key + ((size_t)b * HW + ch * 512 + w * 128) * 16;
    float acc[16][4];
    #pragma unroll
    for (int p = 0; p < 16; p++)
        #pragma unroll
        for (int i = 0; i < 4; i++) acc[p][i] = 0.f;
    #pragma unroll 4
    for (int blk = 0; blk < 32; blk++){
        int tok = blk * 4 + g;
        float4 kv = kp[tok * 16 + cg];
        const unsigned int* wp = &wlds[w * 128 + tok][0];
        uint2 q0 = *(const uint2*)&wp[0];
        uint2 q1 = *(const uint2*)&wp[2];
        uint2 q2 = *(const uint2*)&wp[4];
        uint2 q3 = *(const uint2*)&wp[6];
        unsigned int ww[8] = {q0.x, q0.y, q1.x, q1.y, q2.x, q2.y, q3.x, q3.y};
        #pragma unroll
        for (int p2 = 0; p2 < 8; p2++){
            float wa = bfbits2f(ww[p2] & 0xffffu);
            float wb = bfbits2f(ww[p2] >> 16);
            int pa = 2*p2, pb2 = 2*p2 + 1;
            acc[pa][0] = fmaf(wa, kv.x, acc[pa][0]);
            acc[pa][1] = fmaf(wa, kv.y, acc[pa][1]);
            acc[pa][2] = fmaf(wa, kv.z, acc[pa][2]);
            acc[pa][3] = fmaf(wa, kv.w, acc[pa][3]);
            acc[pb2][0] = fmaf(wb, kv.x, acc[pb2][0]);
            acc[pb2][1] = fmaf(wb, kv.y, acc[pb2][1]);
            acc[pb2][2] = fmaf(wb, kv.z, acc[pb2][2]);
            acc[pb2][3] = fmaf(wb, kv.w, acc[pb2][3]);
        }
    }
    #pragma unroll
    for (int p = 0; p < 16; p++)
        #pragma unroll
        for (int i = 0; i < 4; i++){
            acc[p][i] += __shfl_xor(acc[p][i], 16, 64);
            acc[p][i] += __shfl_xor(acc[p][i], 32, 64);
        }
    __syncthreads();
    float (*red)[16][68] = (float (*)[16][68])wlds;
    if (g == 0){
        #pragma unroll
        for (int p = 0; p < 16; p++)
            *(float4*)&red[w][p][cg*4] =
                make_float4(acc[p][0], acc[p][1], acc[p][2], acc[p][3]);
    }
    __syncthreads();
    size_t obase = ((size_t)(b * 128 + ch)) * 1024;
    for (int idx = t; idx < 1024; idx += 256){
        int p = idx >> 6, c = idx & 63;
        ppart[obase + idx] = red[0][p][c] + red[1][p][c] + red[2][p][c] + red[3][p][c];
    }
}

// ---------------- K6: apply per-chunk softmax scale + reduce -> proto (128 blocks) ----------------
__global__ __launch_bounds__(256) void k_reduce(
    const float* __restrict__ smpart, const float* __restrict__ ppart,
    float* __restrict__ proto)
{
    int p = blockIdx.x, b = blockIdx.y, t = threadIdx.x;
    __shared__ float arr[128], flv[128], partial[4][64];
    float Mt = -1e30f, St = 0.f;
    if (t < 128){
        Mt = smpart[((b*16 + p)*128 + t)*2];
        St = smpart[((b*16 + p)*128 + t)*2 + 1];
        arr[t] = Mt;
    }
    __syncthreads();
    for (int s = 64; s > 0; s >>= 1){
        if (t < s) arr[t] = fmaxf(arr[t], arr[t + s]);
        __syncthreads();
    }
    float M = arr[0];
    __syncthreads();
    if (t < 128) arr[t] = St * __expf(Mt - M);
    __syncthreads();
    for (int s = 64; s > 0; s >>= 1){
        if (t < s) arr[t] += arr[t + s];
        __syncthreads();
    }
    float Stot = arr[0];
    __syncthreads();
    if (t < 128) flv[t] = __expf(Mt - M) / Stot;
    __syncthreads();
    int c = t & 63, half = t >> 6;
    float acc = 0.f;
    #pragma unroll 8
    for (int j = 0; j < 32; j++){
        int ch = half * 32 + j;
        acc += flv[ch] * ppart[((size_t)(b * 128 + ch)) * 1024 + p * 64 + c];
    }
    partial[half][c] = acc;
    __syncthreads();
    if (t < 64)
        proto[b * 1024 + p * 64 + t] =
            (partial[0][t] + partial[1][t]) + (partial[2][t] + partial[3][t]);
}

// ---------------- K7: gate MLPs + sigmoid + LayerNorm ----------------
__global__ __launch_bounds__(256) void k_gate(
    const float* __restrict__ proto, const float* __restrict__ query,
    const float* __restrict__ w1, const float* __restrict__ bb1,
    const float* __restrict__ w2, const float* __restrict__ bb2,
    const float* __restrict__ gw1, const float* __restrict__ gb1,
    const float* __restrict__ gw2, const float* __restrict__ gb2,
    const float* __restrict__ lng, const float* __restrict__ lnb,
    float* __restrict__ out)
{
    __shared__ float z[16][64], h1[16][64], loc[16][64], g[64], hg[64], glb[64];
    int b = blockIdx.x, t = threadIdx.x;
    for (int idx = t; idx < 1024; idx += 256)
        z[idx >> 6][idx & 63] = proto[b * 1024 + idx] + query[b * 1024 + idx];
    __syncthreads();
    for (int idx = t; idx < 1024; idx += 256){
        int p = idx >> 6, j = idx & 63;
        float acc = bb1[j];
        for (int i = 0; i < 64; i++) acc += z[p][i] * w1[j * 64 + i];
        h1[p][j] = relu_f(acc);
    }
    if (t < 64){
        float sg = 0.f;
        for (int p = 0; p < 16; p++) sg += z[p][t];
        g[t] = sg * (1.f / 16.f);
    }
    __syncthreads();
    for (int idx = t; idx < 1024; idx += 256){
        int p = idx >> 6, k = idx & 63;
        float acc = bb2[k];
        for (int j = 0; j < 64; j++) acc += h1[p][j] * w2[k * 64 + j];
        loc[p][k] = acc;
    }
    if (t < 64){
        float acc = gb1[t];
        for (int i = 0; i < 64; i++) acc += g[i] * gw1[t * 64 + i];
        hg[t] = relu_f(acc);
    }
    __syncthreads();
    if (t < 64){
        float acc = gb2[t];
        for (int j = 0; j < 64; j++) acc += hg[j] * gw2[t * 64 + j];
        glb[t] = acc;
    }
    __syncthreads();
    for (int idx = t; idx < 1024; idx += 256){
        int p = idx >> 6, c = idx & 63;
        float a = loc[p][c] + glb[c];
        float sg = 1.f / (1.f + expf(-a));
        float q = query[b * 1024 + idx];
        h1[p][c] = q * sg + q;
    }
    __syncthreads();
    if (t < 16){
        int p = t;
        float mu = 0.f;
        for (int c = 0; c < 64; c++) mu += h1[p][c];
        mu *= (1.f / 64.f);
        float var = 0.f;
        for (int c = 0; c < 64; c++){ float d = h1[p][c] - mu; var += d * d; }
        var *= (1.f / 64.f);
        float rstd = rsqrtf(var + 1e-5f);
        for (int c = 0; c < 64; c++)
            out[b * 1024 + p * 64 + c] = (h1[p][c] - mu) * rstd * lng[c] + lnb[c];
    }
}

extern "C" void kernel_launch(void* const* d_in, const int* in_sizes, int n_in,
                              void* d_out, int out_size, void* d_ws, size_t ws_size,
                              hipStream_t stream){
    (void)in_sizes; (void)n_in; (void)out_size; (void)ws_size;
    const float* feat   = (const float*)d_in[0];
    const float* query  = (const float*)d_in[1];
    const float* key    = (const float*)d_in[2];
    const float* dw_w   = (const float*)d_in[3];
    const float* bn1_g  = (const float*)d_in[4];
    const float* bn1_b  = (const float*)d_in[5];
    const float* bn1_m  = (const float*)d_in[6];
    const float* bn1_v  = (const float*)d_in[7];
    const float* pw_w   = (const float*)d_in[8];
    const float* bn2_g  = (const float*)d_in[9];
    const float* bn2_b  = (const float*)d_in[10];
    const float* bn2_m  = (const float*)d_in[11];
    const float* bn2_v  = (const float*)d_in[12];
    const float* aff_w  = (const float*)d_in[13];
    const float* loc_w1 = (const float*)d_in[14];
    const float* loc_b1 = (const float*)d_in[15];
    const float* loc_w2 = (const float*)d_in[16];
    const float* loc_b2 = (const float*)d_in[17];
    const float* glb_w1 = (const float*)d_in[18];
    const float* glb_b1 = (const float*)d_in[19];
    const float* glb_w2 = (const float*)d_in[20];
    const float* glb_b2 = (const float*)d_in[21];
    const float* ln_g   = (const float*)d_in[22];
    const float* ln_b   = (const float*)d_in[23];
    const float* topo   = (const float*)d_in[24];
    const float* orient = (const float*)d_in[25];
    const float* proto_orient = (const float*)d_in[26];
    float* out = (float*)d_out;
    float* ws  = (float*)d_ws;

    float* ei      = ws;                                       // 524288 f
    unsigned short* logitsH = (unsigned short*)(ws + 1048576); // 8,388,608 ushort
    float* ppart   = ws + 5242880;                             // 1,048,576 f
    float* k3part  = ws + 6291456;                             // 1024
    float* smpart  = ws + 6292480;                             // 32768
    float* proto   = ws + 6325248;                             // 8192
    float* scsh    = ws + 6333440;                             // 256
    unsigned short* pwA  = (unsigned short*)(ws + 6333696);    // 4096 ushort
    unsigned short* affA = (unsigned short*)(ws + 6335744);    // 1024 ushort

    k_prep<<<1, 256, 0, stream>>>(pw_w, aff_w, bn1_g, bn1_b, bn1_m, bn1_v,
                                  bn2_g, bn2_b, bn2_m, bn2_v, scsh, pwA, affA);
    k_conv_aff<<<2048, 256, 0, stream>>>(feat, dw_w, scsh, pwA, affA, logitsH, ei);
    k_sobel_stats<<<dim3(64, 8), 256, 0, stream>>>(ei, k3part);
    k_smproto<<<dim3(128, 8), 256, 0, stream>>>(logitsH, ei, k3part, proto_orient,
                                                topo, orient, key, smpart, ppart);
    k_reduce<<<dim3(16, 8), 256, 0, stream>>>(smpart, ppart, proto);
    k_gate<<<8, 256, 0, stream>>>(proto, query, loc_w1, loc_b1, loc_w2, loc_b2,
                                  glb_w1, glb_b1, glb_w2, glb_b2, ln_g, ln_b, out);
}